// Round 1
// baseline (13140.404 us; speedup 1.0000x reference)
//
#include <hip/hip_runtime.h>
#include <cstdint>

// ---- JAX RNG flavor: 1 = partitionable threefry (JAX >= 0.5 default), 0 = legacy split-half
#define JAX_PARTITIONABLE 1

#define OBS_LEN 20
#define PRED_LEN 30
#define NUM_MODES 6
#define BATCH 8192
#define H 256
#define MB (NUM_MODES * BATCH) /* 49152 */

// ---------------- threefry2x32 (exact JAX semantics) ----------------
__host__ __device__ inline void tf2x32(uint32_t k0, uint32_t k1, uint32_t c0, uint32_t c1,
                                       uint32_t& o0, uint32_t& o1) {
  uint32_t ks0 = k0, ks1 = k1, ks2 = k0 ^ k1 ^ 0x1BD11BDAu;
  uint32_t x0 = c0 + ks0, x1 = c1 + ks1;
#define TF_R(x, r) (((x) << (r)) | ((x) >> (32 - (r))))
#define TF_RND(r)  { x0 += x1; x1 = TF_R(x1, r); x1 ^= x0; }
  TF_RND(13) TF_RND(15) TF_RND(26) TF_RND(6)   x0 += ks1; x1 += ks2 + 1u;
  TF_RND(17) TF_RND(29) TF_RND(16) TF_RND(24)  x0 += ks2; x1 += ks0 + 2u;
  TF_RND(13) TF_RND(15) TF_RND(26) TF_RND(6)   x0 += ks0; x1 += ks1 + 3u;
  TF_RND(17) TF_RND(29) TF_RND(16) TF_RND(24)  x0 += ks1; x1 += ks2 + 4u;
  TF_RND(13) TF_RND(15) TF_RND(26) TF_RND(6)   x0 += ks2; x1 += ks0 + 5u;
  o0 = x0; o1 = x1;
#undef TF_RND
#undef TF_R
}

// key for (mode m, step t): jax.random.split(key(42), 180).reshape(6,30)
__device__ inline void step_key(int m, int t, uint32_t& k0, uint32_t& k1) {
#if JAX_PARTITIONABLE
  tf2x32(0u, 42u, 0u, (uint32_t)(m * PRED_LEN + t), k0, k1);
#else
  int i = m * PRED_LEN + t;
  int n0 = 2 * i, n1 = 2 * i + 1;
  uint32_t a0, a1;
  if (n0 < 180) { tf2x32(0u, 42u, (uint32_t)n0, (uint32_t)(n0 + 180), a0, a1); k0 = a0; }
  else          { tf2x32(0u, 42u, (uint32_t)(n0 - 180), (uint32_t)n0, a0, a1); k0 = a1; }
  if (n1 < 180) { tf2x32(0u, 42u, (uint32_t)n1, (uint32_t)(n1 + 180), a0, a1); k1 = a0; }
  else          { tf2x32(0u, 42u, (uint32_t)(n1 - 180), (uint32_t)n1, a0, a1); k1 = a1; }
#endif
}

// 32-bit random draw n of a (8192,40) bernoulli call
__device__ inline uint32_t mask_bits(uint32_t k0, uint32_t k1, uint32_t n) {
#if JAX_PARTITIONABLE
  uint32_t o0, o1;
  tf2x32(k0, k1, 0u, n, o0, o1);
  return o0 ^ o1;
#else
  const uint32_t HALF = (uint32_t)(BATCH * 40 / 2);
  uint32_t o0, o1;
  if (n < HALF) { tf2x32(k0, k1, n, n + HALF, o0, o1); return o0; }
  else          { tf2x32(k0, k1, n - HALF, n, o0, o1); return o1; }
#endif
}

__device__ __forceinline__ float sigf(float x) { return 1.0f / (1.0f + __expf(-x)); }
__device__ __forceinline__ float tanhfast(float x) {
  float e = __expf(-2.0f * fabsf(x));
  float t = (1.0f - e) / (1.0f + e);
  return x >= 0.f ? t : -t;
}

// ---------------- prep: WT = [W_ih | W_hh]^T (296 x 1024), bias = b_ih + b_hh ----------------
__global__ __launch_bounds__(256) void k_prep(const float* __restrict__ Wih, const float* __restrict__ Whh,
                                              const float* __restrict__ bih, const float* __restrict__ bhh,
                                              float* __restrict__ WT, float* __restrict__ bias) {
  int idx = blockIdx.x * 256 + threadIdx.x;
  if (idx < 296 * 1024) {
    int k = idx >> 10, n = idx & 1023;
    WT[idx] = (k < 40) ? Wih[n * 40 + k] : Whh[n * 256 + (k - 40)];
  }
  if (idx < 1024) bias[idx] = bih[idx] + bhh[idx];
}

// ---------------- init h (broadcast state_h over modes) and c (= c0) ----------------
__global__ __launch_bounds__(256) void k_init(const float* __restrict__ state_h, const float* __restrict__ c0,
                                              float* __restrict__ h0, float* __restrict__ cst) {
  size_t idx = (size_t)blockIdx.x * 256 + threadIdx.x;
  const size_t tot = (size_t)MB * H / 4;
  if (idx < tot) {
    float4 cv = ((const float4*)c0)[idx];
    ((float4*)cst)[idx] = cv;
    size_t bh = idx % ((size_t)BATCH * H / 4);
    ((float4*)h0)[idx] = ((const float4*)state_h)[bh];
  }
}

// ---------------- spatial embed + leaky relu + dropout ----------------
// thread -> (m, b, j4) with j4 = group of 4 outputs; x stored as [j4][MB][4] for coalescing
__global__ __launch_bounds__(256) void k_embed(const float* __restrict__ traj_rel, const float* __restrict__ rels,
                                               const float* __restrict__ Wse, const float* __restrict__ bse,
                                               float* __restrict__ xws, int t) {
  __shared__ float sW[1600];
  __shared__ float sb[40];
  int tid = threadIdx.x;
  for (int i = tid; i < 1600; i += 256) sW[i] = Wse[i];
  if (tid < 40) sb[tid] = bse[tid];
  __syncthreads();
  int gid = blockIdx.x * 256 + tid;       // < MB*10
  int b = gid & (BATCH - 1);
  int mj = gid >> 13;
  int j4 = mj % 10, m = mj / 10;
  int j0 = j4 << 2;
  float win[40];
#pragma unroll
  for (int kk = 0; kk < OBS_LEN; kk++) {
    int st = t + kk;
    const float* p = (st < OBS_LEN)
        ? (traj_rel + (((size_t)st * BATCH + b) << 1))
        : (rels + (((size_t)(m * PRED_LEN + (st - OBS_LEN)) * BATCH + b) << 1));
    float2 w = *(const float2*)p;
    win[kk * 2] = w.x; win[kk * 2 + 1] = w.y;
  }
  float a[4] = {sb[j0], sb[j0 + 1], sb[j0 + 2], sb[j0 + 3]};
#pragma unroll
  for (int jj = 0; jj < 4; jj++) {
#pragma unroll
    for (int q4 = 0; q4 < 10; q4++) {
      float4 w = *(const float4*)&sW[(j0 + jj) * 40 + (q4 << 2)];
      a[jj] = fmaf(win[q4 * 4 + 3], w.w,
               fmaf(win[q4 * 4 + 2], w.z,
                fmaf(win[q4 * 4 + 1], w.y,
                 fmaf(win[q4 * 4 + 0], w.x, a[jj]))));
    }
  }
  uint32_t k0, k1;
  step_key(m, t, k0, k1);
  uint32_t nb = (uint32_t)(b * 40 + j0);
  float o[4];
#pragma unroll
  for (int jj = 0; jj < 4; jj++) {
    float v = a[jj];
    v = v > 0.f ? v : 0.01f * v;                       // leaky relu
    uint32_t bits = mask_bits(k0, k1, nb + jj);        // exact JAX bernoulli
    float u = __uint_as_float((bits >> 9) | 0x3f800000u) - 1.0f;
    o[jj] = (u < 0.75f) ? v * 1.3333333730697632f : 0.f;
  }
  *(float4*)(xws + ((size_t)j4 * MB + ((size_t)m * BATCH + b)) * 4) = make_float4(o[0], o[1], o[2], o[3]);
}

// ---------------- fused gates GEMM (49152x296 @ 296x1024) + LSTM pointwise ----------------
// grid (384 row-tiles, 8 col-groups). Tile: 128 rows x (32 hidden x 4 gates).
// Each thread owns 8 rows x (2 hidden x 4 gates) -> i,f,g,o live in-thread for the epilogue.
__global__ __launch_bounds__(256) void k_gates(const float* __restrict__ xws, const float* __restrict__ WT,
                                               const float* __restrict__ bias, const float* __restrict__ hin,
                                               float* __restrict__ hout, float* __restrict__ cst) {
  __shared__ float sA[8][136];
  __shared__ float sB[8][130];
  int tid = threadIdx.x;
  int rt = blockIdx.x, cg = blockIdx.y;
  int row0 = rt * 128;
  int tx = tid & 15, ty = tid >> 4;
  float acc[8][8];
#pragma unroll
  for (int i = 0; i < 8; i++)
#pragma unroll
    for (int j = 0; j < 8; j++) acc[i][j] = 0.f;

  int lrow = tid >> 1;
  int lk4 = (tid & 1) << 2;
  int grow = row0 + lrow;

  for (int kt = 0; kt < 37; kt++) {
    int k0 = kt * 8;
    int kk = k0 + lk4;
    float4 av;
    if (kk < 40) av = *(const float4*)(xws + ((size_t)(kk >> 2) * MB + grow) * 4);
    else         av = *(const float4*)(hin + (size_t)grow * H + (kk - 40));
    float bv[4];
#pragma unroll
    for (int j = 0; j < 4; j++) {
      int e = tid + j * 256;
      int k = e >> 7, cl = e & 127;
      int n = ((cl >> 5) << 8) + (cg << 5) + (cl & 31);  // gate*256 + cg*32 + j
      bv[j] = WT[(size_t)(k0 + k) * 1024 + n];
    }
    __syncthreads();
    sA[lk4 + 0][lrow] = av.x;
    sA[lk4 + 1][lrow] = av.y;
    sA[lk4 + 2][lrow] = av.z;
    sA[lk4 + 3][lrow] = av.w;
#pragma unroll
    for (int j = 0; j < 4; j++) {
      int e = tid + j * 256;
      sB[e >> 7][e & 127] = bv[j];
    }
    __syncthreads();
#pragma unroll
    for (int k = 0; k < 8; k++) {
      float4 a0 = *(const float4*)&sA[k][ty * 8];
      float4 a1 = *(const float4*)&sA[k][ty * 8 + 4];
      float2 b0 = *(const float2*)&sB[k][tx * 2];
      float2 b1 = *(const float2*)&sB[k][32 + tx * 2];
      float2 b2 = *(const float2*)&sB[k][64 + tx * 2];
      float2 b3 = *(const float2*)&sB[k][96 + tx * 2];
      float ar[8] = {a0.x, a0.y, a0.z, a0.w, a1.x, a1.y, a1.z, a1.w};
      float br[8] = {b0.x, b0.y, b1.x, b1.y, b2.x, b2.y, b3.x, b3.y};
#pragma unroll
      for (int i = 0; i < 8; i++)
#pragma unroll
        for (int j = 0; j < 8; j++)
          acc[i][j] = fmaf(ar[i], br[j], acc[i][j]);
    }
  }
  // epilogue: i,f,g,o -> c,h
  int j0 = (cg << 5) + tx * 2;
  float bi[8];
#pragma unroll
  for (int g = 0; g < 4; g++) {
    bi[g * 2]     = bias[g * 256 + j0];
    bi[g * 2 + 1] = bias[g * 256 + j0 + 1];
  }
#pragma unroll
  for (int rr = 0; rr < 8; rr++) {
    int row = row0 + ty * 8 + rr;
    float2 cold = *(const float2*)(cst + (size_t)row * H + j0);
    float cn[2], hn[2];
#pragma unroll
    for (int jj = 0; jj < 2; jj++) {
      float ig = sigf(acc[rr][0 + jj] + bi[0 + jj]);
      float fg = sigf(acc[rr][2 + jj] + bi[2 + jj]);
      float gg = tanhfast(acc[rr][4 + jj] + bi[4 + jj]);
      float og = sigf(acc[rr][6 + jj] + bi[6 + jj]);
      float cv = jj ? cold.y : cold.x;
      float c2 = fg * cv + ig * gg;
      cn[jj] = c2;
      hn[jj] = og * tanhfast(c2);
    }
    *(float2*)(cst + (size_t)row * H + j0)  = make_float2(cn[0], cn[1]);
    *(float2*)(hout + (size_t)row * H + j0) = make_float2(hn[0], hn[1]);
  }
}

// ---------------- pred head: rel = h @ Wp[m].T + bp[m]  (8 lanes per row) ----------------
__global__ __launch_bounds__(256) void k_pred(const float* __restrict__ hsrc, const float* __restrict__ Wp,
                                              const float* __restrict__ bp, float* __restrict__ rels, int t) {
  int tid = threadIdx.x;
  int wv = tid >> 6, lane = tid & 63;
  int grp = lane >> 3, lg = lane & 7;
  int row = blockIdx.x * 32 + wv * 8 + grp;
  int m = row / BATCH, b = row & (BATCH - 1);
  const float* hr = hsrc + (size_t)row * H + lg * 32;
  const float* w0 = Wp + m * 512 + lg * 32;
  const float* w1 = w0 + 256;
  float s0 = 0.f, s1 = 0.f;
#pragma unroll
  for (int q = 0; q < 8; q++) {
    float4 hv = *(const float4*)(hr + q * 4);
    float4 wa = *(const float4*)(w0 + q * 4);
    float4 wb = *(const float4*)(w1 + q * 4);
    s0 += hv.x * wa.x + hv.y * wa.y + hv.z * wa.z + hv.w * wa.w;
    s1 += hv.x * wb.x + hv.y * wb.y + hv.z * wb.z + hv.w * wb.w;
  }
#pragma unroll
  for (int off = 1; off < 8; off <<= 1) {
    s0 += __shfl_xor(s0, off, 64);
    s1 += __shfl_xor(s1, off, 64);
  }
  if (lg == 0) {
    float2 r = make_float2(s0 + bp[m * 2], s1 + bp[m * 2 + 1]);
    *(float2*)(rels + ((size_t)(m * PRED_LEN + t) * BATCH + b) * 2) = r;
  }
}

// ---------------- transpose rels -> pred(B,M,T,2) + confidence net + softmax ----------------
__global__ __launch_bounds__(256) void k_transconf(const float* __restrict__ rels,
                                                   const float* __restrict__ W1, const float* __restrict__ b1,
                                                   const float* __restrict__ W2, const float* __restrict__ b2,
                                                   const float* __restrict__ wfc, const float* __restrict__ bfc,
                                                   float* __restrict__ out) {
  __shared__ float tile[32][361];
  __shared__ float sW1[3600];
  __shared__ float sW2[3600];
  __shared__ float sb1[60], sb2[60], swfc[60];
  __shared__ float sy1[192][61];
  __shared__ float slg[32][6];
  int tid = threadIdx.x;
  for (int i = tid; i < 3600; i += 256) { sW1[i] = W1[i]; sW2[i] = W2[i]; }
  if (tid < 60) { sb1[tid] = b1[tid]; sb2[tid] = b2[tid]; swfc[tid] = wfc[tid]; }
  int b0 = blockIdx.x * 32;
  for (int i = tid; i < 11520; i += 256) {
    int bl = i & 31, c = i >> 5;
    int mm = c / 60, r = c % 60;
    tile[bl][c] = rels[((size_t)((mm * PRED_LEN + (r >> 1)) * BATCH) + (b0 + bl)) * 2 + (r & 1)];
  }
  __syncthreads();
  for (int i = tid; i < 11520; i += 256) {
    int bl = i / 360, c = i % 360;
    out[(size_t)(b0 + bl) * 360 + c] = tile[bl][c];   // pred: flat b*360 + m*60 + t*2 + d
  }
  if (tid < 192) {
    int bl = tid / 6, mm = tid - bl * 6;
    int xb = mm * 60;
    for (int q = 0; q < 60; q++) {
      float acl = sb1[q];
#pragma unroll
      for (int p = 0; p < 60; p++) acl = fmaf(tile[bl][xb + p], sW1[q * 60 + p], acl);
      sy1[tid][q] = fmaxf(acl, 0.f);
    }
    float logit = bfc[0];
    for (int q = 0; q < 60; q++) {
      float acl = sb2[q] + tile[bl][xb + q];
#pragma unroll
      for (int p = 0; p < 60; p++) acl = fmaf(sy1[tid][p], sW2[q * 60 + p], acl);
      logit = fmaf(fmaxf(acl, 0.f), swfc[q], logit);
    }
    slg[bl][mm] = logit;
  }
  __syncthreads();
  if (tid < 32) {
    float mx = slg[tid][0];
#pragma unroll
    for (int m = 1; m < 6; m++) mx = fmaxf(mx, slg[tid][m]);
    float e[6], s = 0.f;
#pragma unroll
    for (int m = 0; m < 6; m++) { e[m] = __expf(slg[tid][m] - mx); s += e[m]; }
    float inv = 1.0f / s;
    size_t base = (size_t)BATCH * 360 + (size_t)(b0 + tid) * 6;
#pragma unroll
    for (int m = 0; m < 6; m++) out[base + m] = e[m] * inv;
  }
}

// ---------------- host ----------------
extern "C" void kernel_launch(void* const* d_in, const int* in_sizes, int n_in,
                              void* d_out, int out_size, void* d_ws, size_t ws_size,
                              hipStream_t stream) {
  const float* traj_rel = (const float*)d_in[1];
  const float* state_h  = (const float*)d_in[2];
  const float* c0       = (const float*)d_in[3];
  const float* Wse      = (const float*)d_in[4];
  const float* bse      = (const float*)d_in[5];
  const float* Wih      = (const float*)d_in[6];
  const float* Whh      = (const float*)d_in[7];
  const float* bih      = (const float*)d_in[8];
  const float* bhh      = (const float*)d_in[9];
  const float* Wp       = (const float*)d_in[10];
  const float* bp       = (const float*)d_in[11];
  const float* W1       = (const float*)d_in[12];
  const float* b1       = (const float*)d_in[13];
  const float* W2       = (const float*)d_in[14];
  const float* b2       = (const float*)d_in[15];
  const float* wfc      = (const float*)d_in[16];
  const float* bfc      = (const float*)d_in[17];
  float* out = (float*)d_out;
  float* ws  = (float*)d_ws;

  size_t off = 0;
  float* h0   = ws + off; off += (size_t)MB * H;
  float* h1   = ws + off; off += (size_t)MB * H;
  float* cst  = ws + off; off += (size_t)MB * H;
  float* xws  = ws + off; off += (size_t)MB * 40;
  float* rels = ws + off; off += (size_t)NUM_MODES * PRED_LEN * BATCH * 2;
  float* WT   = ws + off; off += (size_t)296 * 1024;
  float* bias = ws + off; off += 1024;

  k_prep<<<1184, 256, 0, stream>>>(Wih, Whh, bih, bhh, WT, bias);
  k_init<<<12288, 256, 0, stream>>>(state_h, c0, h0, cst);
  for (int t = 0; t < PRED_LEN; t++) {
    float* hin  = (t & 1) ? h1 : h0;
    float* hout = (t & 1) ? h0 : h1;
    k_embed<<<1920, 256, 0, stream>>>(traj_rel, rels, Wse, bse, xws, t);
    k_gates<<<dim3(384, 8), 256, 0, stream>>>(xws, WT, bias, hin, hout, cst);
    k_pred<<<1536, 256, 0, stream>>>(hout, Wp, bp, rels, t);
  }
  k_transconf<<<256, 256, 0, stream>>>(rels, W1, b1, W2, b2, wfc, bfc, out);
}

// Round 3
// 3525.041 us; speedup vs baseline: 3.7277x; 3.7277x over previous
//
#include <hip/hip_runtime.h>
#include <cstdint>

#define JAX_PARTITIONABLE 1

#define OBS_LEN 20
#define PRED_LEN 30
#define NUM_MODES 6
#define BATCH 8192
#define H 256
#define MB (NUM_MODES * BATCH) /* 49152 */
#define KPAD 320               /* 40 x + 256 h + 24 zero pad */

typedef __attribute__((ext_vector_type(8))) short bf16x8;
typedef __attribute__((ext_vector_type(4))) float f32x4;

// ---------------- threefry2x32 (exact JAX semantics) ----------------
__host__ __device__ inline void tf2x32(uint32_t k0, uint32_t k1, uint32_t c0, uint32_t c1,
                                       uint32_t& o0, uint32_t& o1) {
  uint32_t ks0 = k0, ks1 = k1, ks2 = k0 ^ k1 ^ 0x1BD11BDAu;
  uint32_t x0 = c0 + ks0, x1 = c1 + ks1;
#define TF_R(x, r) (((x) << (r)) | ((x) >> (32 - (r))))
#define TF_RND(r)  { x0 += x1; x1 = TF_R(x1, r); x1 ^= x0; }
  TF_RND(13) TF_RND(15) TF_RND(26) TF_RND(6)   x0 += ks1; x1 += ks2 + 1u;
  TF_RND(17) TF_RND(29) TF_RND(16) TF_RND(24)  x0 += ks2; x1 += ks0 + 2u;
  TF_RND(13) TF_RND(15) TF_RND(26) TF_RND(6)   x0 += ks0; x1 += ks1 + 3u;
  TF_RND(17) TF_RND(29) TF_RND(16) TF_RND(24)  x0 += ks1; x1 += ks2 + 4u;
  TF_RND(13) TF_RND(15) TF_RND(26) TF_RND(6)   x0 += ks2; x1 += ks0 + 5u;
  o0 = x0; o1 = x1;
#undef TF_RND
#undef TF_R
}

__device__ inline void step_key(int m, int t, uint32_t& k0, uint32_t& k1) {
#if JAX_PARTITIONABLE
  tf2x32(0u, 42u, 0u, (uint32_t)(m * PRED_LEN + t), k0, k1);
#else
  int i = m * PRED_LEN + t;
  int n0 = 2 * i, n1 = 2 * i + 1;
  uint32_t a0, a1;
  if (n0 < 180) { tf2x32(0u, 42u, (uint32_t)n0, (uint32_t)(n0 + 180), a0, a1); k0 = a0; }
  else          { tf2x32(0u, 42u, (uint32_t)(n0 - 180), (uint32_t)n0, a0, a1); k0 = a1; }
  if (n1 < 180) { tf2x32(0u, 42u, (uint32_t)n1, (uint32_t)(n1 + 180), a0, a1); k1 = a0; }
  else          { tf2x32(0u, 42u, (uint32_t)(n1 - 180), (uint32_t)n1, a0, a1); k1 = a1; }
#endif
}

__device__ inline uint32_t mask_bits(uint32_t k0, uint32_t k1, uint32_t n) {
#if JAX_PARTITIONABLE
  uint32_t o0, o1;
  tf2x32(k0, k1, 0u, n, o0, o1);
  return o0 ^ o1;
#else
  const uint32_t HALF = (uint32_t)(BATCH * 40 / 2);
  uint32_t o0, o1;
  if (n < HALF) { tf2x32(k0, k1, n, n + HALF, o0, o1); return o0; }
  else          { tf2x32(k0, k1, n - HALF, n, o0, o1); return o1; }
#endif
}

__device__ __forceinline__ float sigf(float x) { return 1.0f / (1.0f + __expf(-x)); }
__device__ __forceinline__ float tanhfast(float x) {
  float e = __expf(-2.0f * fabsf(x));
  float t = (1.0f - e) / (1.0f + e);
  return x >= 0.f ? t : -t;
}
__device__ __forceinline__ ushort f2bf(float f) {
  uint32_t u = __float_as_uint(f);
  uint32_t r = (u + 0x7fffu + ((u >> 16) & 1u)) >> 16;
  return (ushort)r;
}
__device__ __forceinline__ float bf2f(uint32_t u) { return __uint_as_float(u << 16); }

// ---------------- prep: WTb[n'][320] bf16 (reordered cols), bias = b_ih + b_hh ----------------
// n' = cg*128 + nt*16 + col ; gate = nt&3 ; jg = nt>>2 ; N_orig = gate*256 + cg*32 + jg*16 + col
__global__ __launch_bounds__(256) void k_prep(const float* __restrict__ Wih, const float* __restrict__ Whh,
                                              const float* __restrict__ bih, const float* __restrict__ bhh,
                                              ushort* __restrict__ WTb, float* __restrict__ bias) {
  int idx = blockIdx.x * 256 + threadIdx.x;
  if (idx < 1024 * KPAD) {
    int np = idx / KPAD, k = idx - np * KPAD;
    int cg = np >> 7, r = np & 127;
    int nt = r >> 4, col = r & 15;
    int N = (nt & 3) * 256 + cg * 32 + (nt >> 2) * 16 + col;
    float v = (k < 40) ? Wih[N * 40 + k] : (k < 296 ? Whh[N * 256 + (k - 40)] : 0.f);
    WTb[idx] = f2bf(v);
  }
  if (idx < 1024) bias[idx] = bih[idx] + bhh[idx];
}

// ---------------- init: cst=c0 (fp32); A0 h-region = bf16(state_h); zero pads of A0,A1 ----------------
__global__ __launch_bounds__(256) void k_init(const float* __restrict__ state_h, const float* __restrict__ c0,
                                              float* __restrict__ cst, ushort* __restrict__ Ab0,
                                              ushort* __restrict__ Ab1) {
  int idx = blockIdx.x * 256 + threadIdx.x;   // < MB*64
  if (idx < MB * 64) {
    int row = idx >> 6;
    int j4 = (idx & 63) << 2;
    float4 cv = *(const float4*)(c0 + (size_t)idx * 4);
    *(float4*)(cst + (size_t)idx * 4) = cv;
    int b = row & (BATCH - 1);
    float4 hv = *(const float4*)(state_h + (size_t)b * H + j4);
    ushort4 hb = {f2bf(hv.x), f2bf(hv.y), f2bf(hv.z), f2bf(hv.w)};
    *(ushort4*)(Ab0 + (size_t)row * KPAD + 40 + j4) = hb;
  }
  if (idx < MB * 6) {
    int row = idx / 6, p4 = (idx - row * 6) << 2;
    ushort4 z = {0, 0, 0, 0};
    *(ushort4*)(Ab0 + (size_t)row * KPAD + 296 + p4) = z;
    *(ushort4*)(Ab1 + (size_t)row * KPAD + 296 + p4) = z;
  }
}

// ---------------- spatial embed + leaky relu + dropout -> bf16 x slice of A ----------------
__global__ __launch_bounds__(256) void k_embed(const float* __restrict__ traj_rel, const float* __restrict__ rels,
                                               const float* __restrict__ Wse, const float* __restrict__ bse,
                                               ushort* __restrict__ Ax, int t) {
  __shared__ float sW[1600];
  __shared__ float sb[40];
  int tid = threadIdx.x;
  for (int i = tid; i < 1600; i += 256) sW[i] = Wse[i];
  if (tid < 40) sb[tid] = bse[tid];
  __syncthreads();
  int gid = blockIdx.x * 256 + tid;   // < MB
  int b = gid & (BATCH - 1);
  int m = gid >> 13;
  float win[40];
#pragma unroll
  for (int kk = 0; kk < OBS_LEN; kk++) {
    int st = t + kk;
    const float* p = (st < OBS_LEN)
        ? (traj_rel + (((size_t)st * BATCH + b) << 1))
        : (rels + (((size_t)(m * PRED_LEN + (st - OBS_LEN)) * BATCH + b) << 1));
    float2 w = *(const float2*)p;
    win[kk * 2] = w.x; win[kk * 2 + 1] = w.y;
  }
  uint32_t k0, k1;
  step_key(m, t, k0, k1);
  uint32_t nb = (uint32_t)(b * 40);
  ushort* orow = Ax + (size_t)gid * KPAD;
#pragma unroll
  for (int jo = 0; jo < 5; jo++) {
    uint32_t pk[4];
#pragma unroll
    for (int jp = 0; jp < 4; jp++) {
      ushort lo = 0, hi = 0;
#pragma unroll
      for (int ji = 0; ji < 2; ji++) {
        int j = jo * 8 + jp * 2 + ji;
        float a = sb[j];
#pragma unroll
        for (int p = 0; p < 40; p += 4) {
          float4 w = *(const float4*)&sW[j * 40 + p];
          a = fmaf(win[p + 3], w.w, fmaf(win[p + 2], w.z, fmaf(win[p + 1], w.y, fmaf(win[p], w.x, a))));
        }
        a = a > 0.f ? a : 0.01f * a;
        uint32_t bits = mask_bits(k0, k1, nb + (uint32_t)j);
        float u = __uint_as_float((bits >> 9) | 0x3f800000u) - 1.0f;
        ushort r = (u < 0.75f) ? f2bf(a * 1.3333333730697632f) : (ushort)0;
        if (ji == 0) lo = r; else hi = r;
      }
      pk[jp] = (uint32_t)lo | ((uint32_t)hi << 16);
    }
    uint4 v = {pk[0], pk[1], pk[2], pk[3]};
    *(uint4*)(orow + jo * 8) = v;
  }
}

// ---------------- MFMA gates GEMM (49152x320 @ 320x1024 bf16) + fused LSTM pointwise ----------------
// grid (384 row-tiles, 8 col-groups), 256 thr = 4 waves. Tile 128 rows x 128 cols.
// Each K-chunk row = 32 bf16 = 64 B, staged by 2 threads x 32 B (two uint4 each).
__global__ __launch_bounds__(256) void k_gates(const ushort* __restrict__ Ain, const ushort* __restrict__ WTb,
                                               const float* __restrict__ bias, float* __restrict__ cst,
                                               ushort* __restrict__ Anext) {
  __shared__ __align__(16) ushort lA[2][128][40];   // K-chunk 32, padded to 40
  __shared__ __align__(16) ushort lB[2][128][40];
  int tid = threadIdx.x;
  int w = tid >> 6, lane = tid & 63;
  int row0 = blockIdx.x * 128;
  int cg = blockIdx.y;
  int sr = tid >> 1, sh = (tid & 1) << 4;   // staging: row, half (16 ushorts = 32 B)
  const ushort* gA = Ain + (size_t)(row0 + sr) * KPAD + sh;
  const ushort* gB = WTb + (size_t)(cg * 128 + sr) * KPAD + sh;

  f32x4 zero = {0.f, 0.f, 0.f, 0.f};
  f32x4 acc[2][8];
#pragma unroll
  for (int i = 0; i < 2; i++)
#pragma unroll
    for (int j = 0; j < 8; j++) acc[i][j] = zero;

  uint4 ra0 = *(const uint4*)gA;
  uint4 ra1 = *(const uint4*)(gA + 8);
  uint4 rb0 = *(const uint4*)gB;
  uint4 rb1 = *(const uint4*)(gB + 8);
  *(uint4*)&lA[0][sr][sh] = ra0;
  *(uint4*)&lA[0][sr][sh + 8] = ra1;
  *(uint4*)&lB[0][sr][sh] = rb0;
  *(uint4*)&lB[0][sr][sh + 8] = rb1;
  __syncthreads();

  int fm = lane & 15, fq = lane >> 4;
  for (int kt = 0; kt < 10; kt++) {
    int cur = kt & 1;
    if (kt < 9) {
      ra0 = *(const uint4*)(gA + (kt + 1) * 32);
      ra1 = *(const uint4*)(gA + (kt + 1) * 32 + 8);
      rb0 = *(const uint4*)(gB + (kt + 1) * 32);
      rb1 = *(const uint4*)(gB + (kt + 1) * 32 + 8);
    }
    bf16x8 af[2], bfr[8];
#pragma unroll
    for (int rt = 0; rt < 2; rt++) af[rt] = *(const bf16x8*)&lA[cur][w * 32 + rt * 16 + fm][fq * 8];
#pragma unroll
    for (int nt = 0; nt < 8; nt++) bfr[nt] = *(const bf16x8*)&lB[cur][nt * 16 + fm][fq * 8];
#pragma unroll
    for (int rt = 0; rt < 2; rt++)
#pragma unroll
      for (int nt = 0; nt < 8; nt++)
        acc[rt][nt] = __builtin_amdgcn_mfma_f32_16x16x32_bf16(af[rt], bfr[nt], acc[rt][nt], 0, 0, 0);
    if (kt < 9) {
      *(uint4*)&lA[cur ^ 1][sr][sh] = ra0;
      *(uint4*)&lA[cur ^ 1][sr][sh + 8] = ra1;
      *(uint4*)&lB[cur ^ 1][sr][sh] = rb0;
      *(uint4*)&lB[cur ^ 1][sr][sh + 8] = rb1;
      __syncthreads();
    }
  }

  // epilogue: C/D layout col=lane&15, row=(lane>>4)*4+reg
#pragma unroll
  for (int jg = 0; jg < 2; jg++) {
    int jh = cg * 32 + jg * 16 + fm;
    float bi = bias[jh], bfg = bias[256 + jh], bg = bias[512 + jh], bo = bias[768 + jh];
#pragma unroll
    for (int rt = 0; rt < 2; rt++) {
#pragma unroll
      for (int reg = 0; reg < 4; reg++) {
        int row = row0 + w * 32 + rt * 16 + fq * 4 + reg;
        float gi = acc[rt][jg * 4 + 0][reg] + bi;
        float gf = acc[rt][jg * 4 + 1][reg] + bfg;
        float gg = acc[rt][jg * 4 + 2][reg] + bg;
        float go = acc[rt][jg * 4 + 3][reg] + bo;
        size_t ci = (size_t)row * H + jh;
        float cv = cst[ci];
        float c2 = sigf(gf) * cv + sigf(gi) * tanhfast(gg);
        cst[ci] = c2;
        float hn = sigf(go) * tanhfast(c2);
        Anext[(size_t)row * KPAD + 40 + jh] = f2bf(hn);
      }
    }
  }
}

// ---------------- pred head: rel = h @ Wp[m].T + bp[m]  (bf16 h, 8 lanes per row) ----------------
__global__ __launch_bounds__(256) void k_pred(const ushort* __restrict__ hsrc, const float* __restrict__ Wp,
                                              const float* __restrict__ bp, float* __restrict__ rels, int t) {
  int tid = threadIdx.x;
  int wv = tid >> 6, lane = tid & 63;
  int grp = lane >> 3, lg = lane & 7;
  int row = blockIdx.x * 32 + wv * 8 + grp;
  int m = row / BATCH, b = row & (BATCH - 1);
  const ushort* hr = hsrc + (size_t)row * KPAD + 40 + lg * 32;
  const float* w0 = Wp + m * 512 + lg * 32;
  const float* w1 = w0 + 256;
  float s0 = 0.f, s1 = 0.f;
#pragma unroll
  for (int q = 0; q < 4; q++) {
    uint4 hv = *(const uint4*)(hr + q * 8);
    float h0 = bf2f(hv.x & 0xffffu), h1 = bf2f(hv.x >> 16);
    float h2 = bf2f(hv.y & 0xffffu), h3 = bf2f(hv.y >> 16);
    float h4 = bf2f(hv.z & 0xffffu), h5 = bf2f(hv.z >> 16);
    float h6 = bf2f(hv.w & 0xffffu), h7 = bf2f(hv.w >> 16);
    float4 wa0 = *(const float4*)(w0 + q * 8);
    float4 wa1 = *(const float4*)(w0 + q * 8 + 4);
    float4 wb0 = *(const float4*)(w1 + q * 8);
    float4 wb1 = *(const float4*)(w1 + q * 8 + 4);
    s0 += h0 * wa0.x + h1 * wa0.y + h2 * wa0.z + h3 * wa0.w
        + h4 * wa1.x + h5 * wa1.y + h6 * wa1.z + h7 * wa1.w;
    s1 += h0 * wb0.x + h1 * wb0.y + h2 * wb0.z + h3 * wb0.w
        + h4 * wb1.x + h5 * wb1.y + h6 * wb1.z + h7 * wb1.w;
  }
#pragma unroll
  for (int off = 1; off < 8; off <<= 1) {
    s0 += __shfl_xor(s0, off, 64);
    s1 += __shfl_xor(s1, off, 64);
  }
  if (lg == 0) {
    float2 r = make_float2(s0 + bp[m * 2], s1 + bp[m * 2 + 1]);
    *(float2*)(rels + ((size_t)(m * PRED_LEN + t) * BATCH + b) * 2) = r;
  }
}

// ---------------- transpose rels -> pred(B,M,T,2) + confidence net + softmax ----------------
__global__ __launch_bounds__(256) void k_transconf(const float* __restrict__ rels,
                                                   const float* __restrict__ W1, const float* __restrict__ b1,
                                                   const float* __restrict__ W2, const float* __restrict__ b2,
                                                   const float* __restrict__ wfc, const float* __restrict__ bfc,
                                                   float* __restrict__ out) {
  __shared__ float tile[32][361];
  __shared__ float sW1[3600];
  __shared__ float sW2[3600];
  __shared__ float sb1[60], sb2[60], swfc[60];
  __shared__ float sy1[192][61];
  __shared__ float slg[32][6];
  int tid = threadIdx.x;
  for (int i = tid; i < 3600; i += 256) { sW1[i] = W1[i]; sW2[i] = W2[i]; }
  if (tid < 60) { sb1[tid] = b1[tid]; sb2[tid] = b2[tid]; swfc[tid] = wfc[tid]; }
  int b0 = blockIdx.x * 32;
  for (int i = tid; i < 11520; i += 256) {
    int bl = i & 31, c = i >> 5;
    int mm = c / 60, r = c % 60;
    tile[bl][c] = rels[((size_t)((mm * PRED_LEN + (r >> 1)) * BATCH) + (b0 + bl)) * 2 + (r & 1)];
  }
  __syncthreads();
  for (int i = tid; i < 11520; i += 256) {
    int bl = i / 360, c = i % 360;
    out[(size_t)(b0 + bl) * 360 + c] = tile[bl][c];
  }
  if (tid < 192) {
    int bl = tid / 6, mm = tid - bl * 6;
    int xb = mm * 60;
    for (int q = 0; q < 60; q++) {
      float acl = sb1[q];
#pragma unroll
      for (int p = 0; p < 60; p++) acl = fmaf(tile[bl][xb + p], sW1[q * 60 + p], acl);
      sy1[tid][q] = fmaxf(acl, 0.f);
    }
    float logit = bfc[0];
    for (int q = 0; q < 60; q++) {
      float acl = sb2[q] + tile[bl][xb + q];
#pragma unroll
      for (int p = 0; p < 60; p++) acl = fmaf(sy1[tid][p], sW2[q * 60 + p], acl);
      logit = fmaf(fmaxf(acl, 0.f), swfc[q], logit);
    }
    slg[bl][mm] = logit;
  }
  __syncthreads();
  if (tid < 32) {
    float mx = slg[tid][0];
#pragma unroll
    for (int m = 1; m < 6; m++) mx = fmaxf(mx, slg[tid][m]);
    float e[6], s = 0.f;
#pragma unroll
    for (int m = 0; m < 6; m++) { e[m] = __expf(slg[tid][m] - mx); s += e[m]; }
    float inv = 1.0f / s;
    size_t base = (size_t)BATCH * 360 + (size_t)(b0 + tid) * 6;
#pragma unroll
    for (int m = 0; m < 6; m++) out[base + m] = e[m] * inv;
  }
}

// ---------------- host ----------------
extern "C" void kernel_launch(void* const* d_in, const int* in_sizes, int n_in,
                              void* d_out, int out_size, void* d_ws, size_t ws_size,
                              hipStream_t stream) {
  const float* traj_rel = (const float*)d_in[1];
  const float* state_h  = (const float*)d_in[2];
  const float* c0       = (const float*)d_in[3];
  const float* Wse      = (const float*)d_in[4];
  const float* bse      = (const float*)d_in[5];
  const float* Wih      = (const float*)d_in[6];
  const float* Whh      = (const float*)d_in[7];
  const float* bih      = (const float*)d_in[8];
  const float* bhh      = (const float*)d_in[9];
  const float* Wp       = (const float*)d_in[10];
  const float* bp       = (const float*)d_in[11];
  const float* W1       = (const float*)d_in[12];
  const float* b1       = (const float*)d_in[13];
  const float* W2       = (const float*)d_in[14];
  const float* b2       = (const float*)d_in[15];
  const float* wfc      = (const float*)d_in[16];
  const float* bfc      = (const float*)d_in[17];
  float* out = (float*)d_out;

  float* cst  = (float*)d_ws;                           // MB*H fp32
  float* rels = cst + (size_t)MB * H;                   // M*T*B*2 fp32
  float* bias = rels + (size_t)NUM_MODES * PRED_LEN * BATCH * 2;  // 1024 fp32
  ushort* WTb = (ushort*)(bias + 1024);                 // 1024*320 bf16
  ushort* Ab0 = WTb + (size_t)1024 * KPAD;              // MB*320 bf16
  ushort* Ab1 = Ab0 + (size_t)MB * KPAD;

  k_prep<<<1280, 256, 0, stream>>>(Wih, Whh, bih, bhh, WTb, bias);
  k_init<<<12288, 256, 0, stream>>>(state_h, c0, cst, Ab0, Ab1);
  for (int t = 0; t < PRED_LEN; t++) {
    ushort* Acur  = (t & 1) ? Ab1 : Ab0;
    ushort* Anext = (t & 1) ? Ab0 : Ab1;
    k_embed<<<192, 256, 0, stream>>>(traj_rel, rels, Wse, bse, Acur, t);
    k_gates<<<dim3(384, 8), 256, 0, stream>>>(Acur, WTb, bias, cst, Anext);
    k_pred<<<1536, 256, 0, stream>>>(Anext, Wp, bp, rels, t);
  }
  k_transconf<<<256, 256, 0, stream>>>(rels, W1, b1, W2, b2, wfc, bfc, out);
}